// Round 6
// baseline (323.252 us; speedup 1.0000x reference)
//
#include <hip/hip_runtime.h>
#include <hip/hip_bf16.h>

// ---------------- problem constants ----------------
#define T_TOK 2048
#define DM    2048
#define FF    1408
#define NE    8
#define MT_ROUTED 40          // padded routed slot capacity / 128
#define MT_TOTAL  56          // + 2048/128 shared-expert tiles
#define ROUTED_CAP 5120
#define NSLOT 7168

typedef unsigned short u16;
typedef __attribute__((ext_vector_type(4))) u16 u16x4;
typedef __attribute__((ext_vector_type(8))) short bf16x8;
typedef __attribute__((ext_vector_type(4))) float f32x4;

__device__ __forceinline__ u16 f2bf(float f) {
    unsigned u = __float_as_uint(f);
    unsigned r = (u + 0x7FFFu + ((u >> 16) & 1u)) >> 16;
    return (u16)r;
}
__device__ __forceinline__ float bf2f(u16 v) {
    return __uint_as_float(((unsigned)v) << 16);
}

__device__ __forceinline__ void gll16(const void* g, void* l) {
    __builtin_amdgcn_global_load_lds((const __attribute__((address_space(1))) void*)g,
                                     (__attribute__((address_space(3))) void*)l, 16, 0, 0);
}

// ---------------- workspace layout (bytes) ----------------
constexpr size_t SZ_XB  = (size_t)T_TOK * DM * 2;      // x bf16
constexpr size_t SZ_WE  = (size_t)NE * DM * FF * 2;    // one routed weight set, bf16
constexpr size_t SZ_SW  = (size_t)DM * FF * 2;         // one shared weight, bf16
constexpr size_t SZ_H   = (size_t)NSLOT * FF * 2;      // h bf16
constexpr size_t SZ_DN  = (size_t)NSLOT * DM * 2;      // down partials bf16

constexpr size_t OFF_XB   = 0;
constexpr size_t OFF_WGT  = OFF_XB + SZ_XB;
constexpr size_t OFF_WUT  = OFF_WGT + SZ_WE;
constexpr size_t OFF_WDT  = OFF_WUT + SZ_WE;
constexpr size_t OFF_SWG  = OFF_WDT + SZ_WE;
constexpr size_t OFF_SWU  = OFF_SWG + SZ_SW;
constexpr size_t OFF_SWD  = OFF_SWU + SZ_SW;
constexpr size_t OFF_H    = OFF_SWD + SZ_SW;
constexpr size_t OFF_DN   = OFF_H + SZ_H;
constexpr size_t OFF_TID  = OFF_DN + SZ_DN;              // topk ids   [T,2] int
constexpr size_t OFF_TW   = OFF_TID + (size_t)T_TOK*2*4; // topk w     [T,2] f32
constexpr size_t OFF_PERM = OFF_TW  + (size_t)T_TOK*2*4; // slot->token
constexpr size_t OFF_SW_S = OFF_PERM + (size_t)ROUTED_CAP*4; // slot gate w
constexpr size_t OFF_TKS  = OFF_SW_S + (size_t)ROUTED_CAP*4; // (t,k)->slot
constexpr size_t OFF_TE   = OFF_TKS + (size_t)T_TOK*2*4;     // tile -> expert

// ---------------- merged batched transpose-convert (XOR-swizzled LDS) ----------------
// chunk position = cc ^ perm(r), perm(r) = (r>>2) ^ ((r&3)<<2).
// Write: per-row permutation -> conflict-free. Read: rows 4m+j at fixed col ->
// perm = m ^ (j<<2) -> 16 distinct chunks -> 16 distinct banks (row stride = 32 words).
__global__ void tcvt_kernel(const float* __restrict__ wg, const float* __restrict__ wu,
                            const float* __restrict__ swg, const float* __restrict__ swu,
                            const float* __restrict__ wd, const float* __restrict__ swd,
                            u16* __restrict__ wgT, u16* __restrict__ wuT,
                            u16* __restrict__ swgT, u16* __restrict__ swuT,
                            u16* __restrict__ wdT, u16* __restrict__ swdT) {
    __shared__ u16x4 tile[64][16];    // 8 KB
    const int z = blockIdx.z;
    const size_t msz = (size_t)DM * FF;
    const float* s; u16* d; int R, C, trow, tcol;
    if (z < 18) {
        R = DM; C = FF;
        trow = blockIdx.x / 22; tcol = blockIdx.x % 22;   // 32 x 22 tiles
        if (z < 8)       { s = wg + (size_t)z * msz;       d = wgT + (size_t)z * msz; }
        else if (z < 16) { s = wu + (size_t)(z - 8) * msz; d = wuT + (size_t)(z - 8) * msz; }
        else if (z == 16){ s = swg;                         d = swgT; }
        else             { s = swu;                         d = swuT; }
    } else {
        R = FF; C = DM;
        trow = blockIdx.x / 32; tcol = blockIdx.x % 32;   // 22 x 32 tiles
        if (z < 26) { s = wd + (size_t)(z - 18) * msz; d = wdT + (size_t)(z - 18) * msz; }
        else        { s = swd;                          d = swdT; }
    }
    const int r0 = trow * 64, c0 = tcol * 64;
    const int tr = threadIdx.x >> 4;        // 0..15
    const int cc = threadIdx.x & 15;        // chunk col 0..15
#pragma unroll
    for (int i = 0; i < 4; i++) {
        const int r = tr + i * 16;
        const float4 v = *(const float4*)(s + (size_t)(r0 + r) * C + (c0 + cc * 4));
        u16x4 o; o[0] = f2bf(v.x); o[1] = f2bf(v.y); o[2] = f2bf(v.z); o[3] = f2bf(v.w);
        const int perm = ((r >> 2) ^ ((r & 3) << 2)) & 15;
        tile[r][cc ^ perm] = o;
    }
    __syncthreads();
#pragma unroll
    for (int i = 0; i < 4; i++) {
        const int c = tr + i * 16;
        const int ch = c >> 2, cl = c & 3;
        u16x4 o;
#pragma unroll
        for (int j = 0; j < 4; j++) {
            // row = cc*4 + j; perm(row) = cc ^ (j<<2)
            o[j] = tile[cc * 4 + j][ch ^ cc ^ (j << 2)][cl];
        }
        *(u16x4*)(d + (size_t)(c0 + c) * R + (r0 + cc * 4)) = o;
    }
}

// ---------------- router (+ fused x -> bf16 convert) ----------------
__global__ void router_kernel(const float* __restrict__ x, const float* __restrict__ gw,
                              u16* __restrict__ xb,
                              int* __restrict__ topk_id, float* __restrict__ topk_w) {
    const int wv = threadIdx.x >> 6, l = threadIdx.x & 63;
    const int t = blockIdx.x * 4 + wv;
    const float* xt = x + (size_t)t * DM;
    u16* xbt = xb + (size_t)t * DM;
    float acc[NE] = {0.f,0.f,0.f,0.f,0.f,0.f,0.f,0.f};
    for (int d = l * 4; d < DM; d += 256) {
        const float4 xv = *(const float4*)(xt + d);
        u16x4 o; o[0] = f2bf(xv.x); o[1] = f2bf(xv.y); o[2] = f2bf(xv.z); o[3] = f2bf(xv.w);
        *(u16x4*)(xbt + d) = o;
#pragma unroll
        for (int e = 0; e < NE; e++) {
            const float4 w4 = *(const float4*)(gw + e * DM + d);
            acc[e] += xv.x * w4.x + xv.y * w4.y + xv.z * w4.z + xv.w * w4.w;
        }
    }
#pragma unroll
    for (int e = 0; e < NE; e++)
#pragma unroll
        for (int off = 32; off > 0; off >>= 1) acc[e] += __shfl_xor(acc[e], off, 64);
    if (l == 0) {
        float m = acc[0];
#pragma unroll
        for (int e = 1; e < NE; e++) m = fmaxf(m, acc[e]);
        float p[NE];
#pragma unroll
        for (int e = 0; e < NE; e++) p[e] = __expf(acc[e] - m);
        int i1 = 0; float b1 = p[0];
#pragma unroll
        for (int e = 1; e < NE; e++) if (p[e] > b1) { b1 = p[e]; i1 = e; }
        int i2 = -1; float b2 = -1.f;
#pragma unroll
        for (int e = 0; e < NE; e++) if (e != i1 && p[e] > b2) { b2 = p[e]; i2 = e; }
        const float s = b1 + b2;
        topk_id[2*t] = i1; topk_id[2*t+1] = i2;
        topk_w[2*t] = b1 / s; topk_w[2*t+1] = b2 / s;
    }
}

// ---------------- deterministic expert scan / permutation (128-padded) ----------------
__global__ void scan_kernel(const int* __restrict__ topk_id, const float* __restrict__ topk_w,
                            int* __restrict__ perm_token, float* __restrict__ slot_w,
                            int* __restrict__ tk_slot, int* __restrict__ tile_e) {
    const int e = blockIdx.x;
    const int tid = threadIdx.x;
    __shared__ int cnt[NE];
    __shared__ int tsum[256];
    int ids[16];
#pragma unroll
    for (int j = 0; j < 16; j++) ids[j] = topk_id[tid * 16 + j];
    if (tid < NE) cnt[tid] = 0;
    __syncthreads();
#pragma unroll
    for (int e2 = 0; e2 < NE; e2++) {
        int c = 0;
#pragma unroll
        for (int j = 0; j < 16; j++) c += (ids[j] == e2);
        if (c) atomicAdd(&cnt[e2], c);
    }
    int mySum = 0;
#pragma unroll
    for (int j = 0; j < 16; j++) mySum += (ids[j] == e);
    tsum[tid] = mySum;
    __syncthreads();
    if (tid == 0) { int run = 0; for (int i = 0; i < 256; i++) { int v = tsum[i]; tsum[i] = run; run += v; } }
    __syncthreads();
    int poff = 0;
#pragma unroll
    for (int e2 = 0; e2 < NE; e2++) { int p = (cnt[e2] + 127) & ~127; if (e2 < e) poff += p; }
    const int padded_e = (cnt[e] + 127) & ~127;
    int run = tsum[tid];
#pragma unroll
    for (int j = 0; j < 16; j++) {
        if (ids[j] == e) {
            const int i = tid * 16 + j;
            const int slot = poff + run;
            perm_token[slot] = i >> 1;
            slot_w[slot] = topk_w[i];
            tk_slot[i] = slot;
            run++;
        }
    }
    for (int r = cnt[e] + tid; r < padded_e; r += 256) { perm_token[poff + r] = 0; slot_w[poff + r] = 0.f; }
    if (tid == 0) for (int tt = poff >> 7; tt < (poff + padded_e) >> 7; tt++) tile_e[tt] = e;
    if (e == 0 && tid == 1) {
        int ptot = 0;
#pragma unroll
        for (int e2 = 0; e2 < NE; e2++) ptot += (cnt[e2] + 127) & ~127;
        for (int tt = ptot >> 7; tt < MT_ROUTED; tt++) tile_e[tt] = -1;
        for (int tt = MT_ROUTED; tt < MT_TOTAL; tt++) tile_e[tt] = 8;
    }
}

// ---------------- GEMM1: 128xM x 64h-cols, single-buffer, XCD-swizzled, 4 blocks/CU ----------------
__global__ __launch_bounds__(256, 4)
void gemm1_kernel(const u16* __restrict__ xb,
                  const u16* __restrict__ wgT, const u16* __restrict__ wuT,
                  const u16* __restrict__ swgT, const u16* __restrict__ swuT,
                  const int* __restrict__ perm_token, const float* __restrict__ slot_w,
                  const int* __restrict__ tile_e, u16* __restrict__ hbuf) {
    const int bid = blockIdx.x;
    const int swz = (bid & 7) * 154 + (bid >> 3);   // 1232 = 8*154
    const int mtile = swz % 56, ntile = swz / 56;   // ntile 0..21
    const int e = tile_e[mtile];
    if (e < 0) return;
    __shared__ u16 lA[128 * 64], lB[128 * 64];
    __shared__ int lTok[128];
    __shared__ float lW[128];
    const int tid = threadIdx.x, l = tid & 63, w = tid >> 6;
    const bool sh = (e == 8);
    const int slot_base = sh ? (ROUTED_CAP + (mtile - MT_ROUTED) * 128) : mtile * 128;
    if (tid < 128) {
        if (sh) { lTok[tid] = (mtile - MT_ROUTED) * 128 + tid; lW[tid] = 1.0f; }
        else    { lTok[tid] = perm_token[slot_base + tid]; lW[tid] = slot_w[slot_base + tid]; }
    }
    __syncthreads();
    const u16* Bg = sh ? swgT : (wgT + (size_t)e * FF * DM);
    const u16* Bu = sh ? swuT : (wuT + (size_t)e * FF * DM);
    const int n0 = ntile * 64;
    const u16* aSrc[4]; const u16* bSrc[4]; int ldsOff[4];
#pragma unroll
    for (int i = 0; i < 4; i++) {
        const int row = i * 32 + w * 8 + (l >> 3);
        const int ch = (l & 7) ^ (row & 7);
        ldsOff[i] = (i * 32 + w * 8) * 64;
        aSrc[i] = xb + (size_t)lTok[row] * DM + ch * 8;
        const u16* bbase = (i < 2) ? (Bg + (size_t)(n0 + row) * DM)
                                   : (Bu + (size_t)(n0 + row - 64) * DM);
        bSrc[i] = bbase + ch * 8;
    }
    f32x4 acc[2][8] = {};
    const int wm = w * 32;
    for (int k0 = 0; k0 < DM; k0 += 64) {
        __syncthreads();
#pragma unroll
        for (int i = 0; i < 4; i++) { gll16(aSrc[i] + k0, lA + ldsOff[i]); gll16(bSrc[i] + k0, lB + ldsOff[i]); }
        __syncthreads();
#pragma unroll
        for (int kk = 0; kk < 64; kk += 32) {
            bf16x8 af[2], bf_[8];
#pragma unroll
            for (int mi = 0; mi < 2; mi++) {
                const int row = wm + mi * 16 + (l & 15);
                const int ch = ((kk >> 3) + (l >> 4)) ^ (row & 7);
                af[mi] = *(const bf16x8*)(lA + row * 64 + ch * 8);
            }
#pragma unroll
            for (int ni = 0; ni < 8; ni++) {
                const int row = ni * 16 + (l & 15);
                const int ch = ((kk >> 3) + (l >> 4)) ^ (row & 7);
                bf_[ni] = *(const bf16x8*)(lB + row * 64 + ch * 8);
            }
#pragma unroll
            for (int mi = 0; mi < 2; mi++)
#pragma unroll
                for (int ni = 0; ni < 8; ni++)
                    acc[mi][ni] = __builtin_amdgcn_mfma_f32_16x16x32_bf16(af[mi], bf_[ni], acc[mi][ni], 0, 0, 0);
        }
    }
#pragma unroll
    for (int mi = 0; mi < 2; mi++)
#pragma unroll
        for (int r = 0; r < 4; r++) {
            const int m = wm + mi * 16 + (l >> 4) * 4 + r;
            const float wgt = lW[m];
#pragma unroll
            for (int ni = 0; ni < 4; ni++) {
                const int n = ni * 16 + (l & 15);
                const float g = acc[mi][ni][r], u = acc[mi][ni + 4][r];
                const float h = g * (1.f / (1.f + __expf(-g))) * u * wgt;
                hbuf[(size_t)(slot_base + m) * FF + n0 + n] = f2bf(h);
            }
        }
}

// ---------------- GEMM2: 128xM x 64xN, single-buffer, XCD-swizzled, 5 blocks/CU ----------------
__global__ __launch_bounds__(256, 5)
void gemm2_kernel(const u16* __restrict__ hbuf, const u16* __restrict__ wdT,
                  const u16* __restrict__ swdT, const int* __restrict__ tile_e,
                  u16* __restrict__ dn) {
    const int bid = blockIdx.x;
    const int swz = (bid & 7) * 224 + (bid >> 3);   // 1792 = 8*224
    const int mtile = swz % 56, ntile = swz / 56;   // ntile 0..31
    const int e = tile_e[mtile];
    if (e < 0) return;
    __shared__ u16 lA[128 * 64], lB[64 * 64];
    const int tid = threadIdx.x, l = tid & 63, w = tid >> 6;
    const bool sh = (e == 8);
    const int slot_base = sh ? (ROUTED_CAP + (mtile - MT_ROUTED) * 128) : mtile * 128;
    const u16* Bp = sh ? swdT : (wdT + (size_t)e * DM * FF);
    const int n0 = ntile * 64;
    const u16* aSrc[4]; const u16* bSrc[2]; int aOff[4], bOff[2];
#pragma unroll
    for (int i = 0; i < 4; i++) {
        const int row = i * 32 + w * 8 + (l >> 3);
        const int ch = (l & 7) ^ (row & 7);
        aOff[i] = (i * 32 + w * 8) * 64;
        aSrc[i] = hbuf + (size_t)(slot_base + row) * FF + ch * 8;
    }
#pragma unroll
    for (int i = 0; i < 2; i++) {
        const int row = i * 32 + w * 8 + (l >> 3);
        const int ch = (l & 7) ^ (row & 7);
        bOff[i] = (i * 32 + w * 8) * 64;
        bSrc[i] = Bp + (size_t)(n0 + row) * FF + ch * 8;
    }
    f32x4 acc[2][4] = {};
    const int wm = w * 32;
    for (int k0 = 0; k0 < FF; k0 += 64) {
        __syncthreads();
#pragma unroll
        for (int i = 0; i < 4; i++) gll16(aSrc[i] + k0, lA + aOff[i]);
#pragma unroll
        for (int i = 0; i < 2; i++) gll16(bSrc[i] + k0, lB + bOff[i]);
        __syncthreads();
#pragma unroll
        for (int kk = 0; kk < 64; kk += 32) {
            bf16x8 af[2], bf_[4];
#pragma unroll
            for (int mi = 0; mi < 2; mi++) {
                const int row = wm + mi * 16 + (l & 15);
                const int ch = ((kk >> 3) + (l >> 4)) ^ (row & 7);
                af[mi] = *(const bf16x8*)(lA + row * 64 + ch * 8);
            }
#pragma unroll
            for (int ni = 0; ni < 4; ni++) {
                const int row = ni * 16 + (l & 15);
                const int ch = ((kk >> 3) + (l >> 4)) ^ (row & 7);
                bf_[ni] = *(const bf16x8*)(lB + row * 64 + ch * 8);
            }
#pragma unroll
            for (int mi = 0; mi < 2; mi++)
#pragma unroll
                for (int ni = 0; ni < 4; ni++)
                    acc[mi][ni] = __builtin_amdgcn_mfma_f32_16x16x32_bf16(af[mi], bf_[ni], acc[mi][ni], 0, 0, 0);
        }
    }
#pragma unroll
    for (int mi = 0; mi < 2; mi++)
#pragma unroll
        for (int r = 0; r < 4; r++) {
            const int m = wm + mi * 16 + (l >> 4) * 4 + r;
#pragma unroll
            for (int ni = 0; ni < 4; ni++) {
                const int n = ni * 16 + (l & 15);
                dn[(size_t)(slot_base + m) * DM + n0 + n] = f2bf(acc[mi][ni][r]);
            }
        }
}

// ---------------- combine: out[t] = dn[s1] + dn[s2] + dn[shared] ----------------
__global__ void combine_kernel(const u16* __restrict__ dn, const int* __restrict__ tk_slot,
                               float* __restrict__ out) {
    const int i = blockIdx.x * 256 + threadIdx.x;
    const int base = i * 8;
    const int t = base >> 11, d = base & 2047;
    const int s1 = tk_slot[2 * t], s2 = tk_slot[2 * t + 1];
    const bf16x8 a = *(const bf16x8*)(dn + (size_t)s1 * DM + d);
    const bf16x8 b = *(const bf16x8*)(dn + (size_t)s2 * DM + d);
    const bf16x8 c = *(const bf16x8*)(dn + (size_t)(ROUTED_CAP + t) * DM + d);
    float o[8];
#pragma unroll
    for (int j = 0; j < 8; j++)
        o[j] = bf2f((u16)a[j]) + bf2f((u16)b[j]) + bf2f((u16)c[j]);
    float4 lo, hi;
    lo.x = o[0]; lo.y = o[1]; lo.z = o[2]; lo.w = o[3];
    hi.x = o[4]; hi.y = o[5]; hi.z = o[6]; hi.w = o[7];
    *(float4*)(out + base) = lo;
    *(float4*)(out + base + 4) = hi;
}

// ---------------- launch ----------------
extern "C" void kernel_launch(void* const* d_in, const int* in_sizes, int n_in,
                              void* d_out, int out_size, void* d_ws, size_t ws_size,
                              hipStream_t stream) {
    (void)in_sizes; (void)n_in; (void)out_size; (void)ws_size;
    const float* x   = (const float*)d_in[0];
    const float* gw  = (const float*)d_in[1];
    const float* wg  = (const float*)d_in[2];
    const float* wu  = (const float*)d_in[3];
    const float* wd  = (const float*)d_in[4];
    const float* swg = (const float*)d_in[5];
    const float* swu = (const float*)d_in[6];
    const float* swd = (const float*)d_in[7];
    float* out = (float*)d_out;
    char* ws = (char*)d_ws;

    u16*   xb    = (u16*)(ws + OFF_XB);
    u16*   wgT   = (u16*)(ws + OFF_WGT);
    u16*   wuT   = (u16*)(ws + OFF_WUT);
    u16*   wdT   = (u16*)(ws + OFF_WDT);
    u16*   swgT  = (u16*)(ws + OFF_SWG);
    u16*   swuT  = (u16*)(ws + OFF_SWU);
    u16*   swdT  = (u16*)(ws + OFF_SWD);
    u16*   hbuf  = (u16*)(ws + OFF_H);
    u16*   dn    = (u16*)(ws + OFF_DN);
    int*   tid_  = (int*)(ws + OFF_TID);
    float* tw    = (float*)(ws + OFF_TW);
    int*   perm  = (int*)(ws + OFF_PERM);
    float* slw   = (float*)(ws + OFF_SW_S);
    int*   tks   = (int*)(ws + OFF_TKS);
    int*   te    = (int*)(ws + OFF_TE);

    router_kernel<<<T_TOK / 4, 256, 0, stream>>>(x, gw, xb, tid_, tw);
    scan_kernel<<<NE, 256, 0, stream>>>(tid_, tw, perm, slw, tks, te);
    tcvt_kernel<<<dim3(704, 1, 27), 256, 0, stream>>>(wg, wu, swg, swu, wd, swd,
                                                      wgT, wuT, swgT, swuT, wdT, swdT);
    gemm1_kernel<<<1232, 256, 0, stream>>>(xb, wgT, wuT, swgT, swuT, perm, slw, te, hbuf);
    gemm2_kernel<<<1792, 256, 0, stream>>>(hbuf, wdT, swdT, te, dn);
    combine_kernel<<<(T_TOK * DM / 8) / 256, 256, 0, stream>>>(dn, tks, out);
}

// Round 7
// 321.893 us; speedup vs baseline: 1.0042x; 1.0042x over previous
//
#include <hip/hip_runtime.h>
#include <hip/hip_bf16.h>

// ---------------- problem constants ----------------
#define T_TOK 2048
#define DM    2048
#define FF    1408
#define NE    8
#define MT_ROUTED 40          // padded routed slot capacity / 128
#define MT_TOTAL  56          // + 2048/128 shared-expert tiles
#define ROUTED_CAP 5120
#define NSLOT 7168

typedef unsigned short u16;
typedef __attribute__((ext_vector_type(4))) u16 u16x4;
typedef __attribute__((ext_vector_type(8))) u16 u16x8;
typedef __attribute__((ext_vector_type(8))) short bf16x8;
typedef __attribute__((ext_vector_type(4))) float f32x4;

__device__ __forceinline__ u16 f2bf(float f) {
    // native conversion (compiler emits v_cvt_pk_bf16_f32 for pairs)
    __hip_bfloat16 b = __float2bfloat16(f);
    union { __hip_bfloat16 b; u16 u; } cv;
    cv.b = b;
    return cv.u;
}
__device__ __forceinline__ float bf2f(u16 v) {
    return __uint_as_float(((unsigned)v) << 16);
}

__device__ __forceinline__ void gll16(const void* g, void* l) {
    __builtin_amdgcn_global_load_lds((const __attribute__((address_space(1))) void*)g,
                                     (__attribute__((address_space(3))) void*)l, 16, 0, 0);
}

// ---------------- workspace layout (bytes) ----------------
constexpr size_t SZ_XB  = (size_t)T_TOK * DM * 2;      // x bf16
constexpr size_t SZ_WE  = (size_t)NE * DM * FF * 2;    // one routed weight set, bf16
constexpr size_t SZ_SW  = (size_t)DM * FF * 2;         // one shared weight, bf16
constexpr size_t SZ_H   = (size_t)NSLOT * FF * 2;      // h bf16
constexpr size_t SZ_DN  = (size_t)NSLOT * DM * 2;      // down partials bf16

constexpr size_t OFF_XB   = 0;
constexpr size_t OFF_WGT  = OFF_XB + SZ_XB;
constexpr size_t OFF_WUT  = OFF_WGT + SZ_WE;
constexpr size_t OFF_WDT  = OFF_WUT + SZ_WE;
constexpr size_t OFF_SWG  = OFF_WDT + SZ_WE;
constexpr size_t OFF_SWU  = OFF_SWG + SZ_SW;
constexpr size_t OFF_SWD  = OFF_SWU + SZ_SW;
constexpr size_t OFF_H    = OFF_SWD + SZ_SW;
constexpr size_t OFF_DN   = OFF_H + SZ_H;
constexpr size_t OFF_TID  = OFF_DN + SZ_DN;              // topk ids   [T,2] int
constexpr size_t OFF_TW   = OFF_TID + (size_t)T_TOK*2*4; // topk w     [T,2] f32
constexpr size_t OFF_PERM = OFF_TW  + (size_t)T_TOK*2*4; // slot->token
constexpr size_t OFF_SW_S = OFF_PERM + (size_t)ROUTED_CAP*4; // slot gate w
constexpr size_t OFF_TKS  = OFF_SW_S + (size_t)ROUTED_CAP*4; // (t,k)->slot
constexpr size_t OFF_TE   = OFF_TKS + (size_t)T_TOK*2*4;     // tile -> expert

// ---------------- merged batched transpose-convert v3 ----------------
// 128x128 tiles: reads 512B/row, writes 256B/row. LDS = 2x2 quadrants of the
// proven conflict-free 64x64 chunk-XOR swizzle, with the r-quadrant bit (rq)
// folded into the perm so the out-gather spreads 16 chunk positions (2-way, free).
__global__ __launch_bounds__(256, 4)
void tcvt_kernel(const float* __restrict__ wg, const float* __restrict__ wu,
                 const float* __restrict__ swg, const float* __restrict__ swu,
                 const float* __restrict__ wd, const float* __restrict__ swd,
                 u16* __restrict__ wgT, u16* __restrict__ wuT,
                 u16* __restrict__ swgT, u16* __restrict__ swuT,
                 u16* __restrict__ wdT, u16* __restrict__ swdT) {
    __shared__ u16x4 tile[2][2][64][16];    // 32 KB
    const int z = blockIdx.z;
    const size_t msz = (size_t)DM * FF;
    const float* s; u16* d; int R, C, trow, tcol;
    if (z < 18) {
        R = DM; C = FF;
        trow = blockIdx.x / 11; tcol = blockIdx.x % 11;   // 16 x 11 tiles of 128
        if (z < 8)       { s = wg + (size_t)z * msz;       d = wgT + (size_t)z * msz; }
        else if (z < 16) { s = wu + (size_t)(z - 8) * msz; d = wuT + (size_t)(z - 8) * msz; }
        else if (z == 16){ s = swg;                         d = swgT; }
        else             { s = swu;                         d = swuT; }
    } else {
        R = FF; C = DM;
        trow = blockIdx.x / 16; tcol = blockIdx.x % 16;   // 11 x 16 tiles of 128
        if (z < 26) { s = wd + (size_t)(z - 18) * msz; d = wdT + (size_t)(z - 18) * msz; }
        else        { s = swd;                          d = swdT; }
    }
    const int r0 = trow * 128, c0 = tcol * 128;
    const int tid = threadIdx.x;
    const int rr = tid >> 5;          // 0..7: row within 8-row round
    const int c4 = tid & 31;          // float4 index within 128 cols
    const int cq = c4 >> 4, cc = c4 & 15;

#pragma unroll
    for (int h = 0; h < 2; h++) {
        float4 v[8];
#pragma unroll
        for (int i = 0; i < 8; i++) {
            const int r = h * 64 + i * 8 + rr;
            v[i] = *(const float4*)(s + (size_t)(r0 + r) * C + (c0 + c4 * 4));
        }
#pragma unroll
        for (int i = 0; i < 8; i++) {
            const int r = h * 64 + i * 8 + rr;
            u16x4 o;
            o[0] = f2bf(v[i].x); o[1] = f2bf(v[i].y);
            o[2] = f2bf(v[i].z); o[3] = f2bf(v[i].w);
            const int pr = ((((r >> 2) ^ ((r & 3) << 2)) & 15) ^ ((r & 64) >> 3));
            tile[r >> 6][cq][r & 63][cc ^ pr] = o;
        }
    }
    __syncthreads();

    const int oc = tid >> 4;          // 0..15: out-row subindex within 16
    const int rc = tid & 15;          // 16B r-chunk (8 r's)
    const int rq = rc >> 3, r7 = rc & 7;
#pragma unroll
    for (int j = 0; j < 8; j++) {
        const int c = j * 16 + oc;
        const int ch = (c >> 2) & 15, cl = c & 3, cq2 = c >> 6;
        u16x8 o;
#pragma unroll
        for (int k = 0; k < 8; k++) {
            const int rl = r7 * 8 + k;
            const int pr = ((((rl >> 2) ^ ((rl & 3) << 2)) & 15) ^ (rq << 3));
            o[k] = tile[rq][cq2][rl][ch ^ pr][cl];
        }
        *(u16x8*)(d + (size_t)(c0 + c) * R + (r0 + rc * 8)) = o;
    }
}

// ---------------- router (+ fused x -> bf16 convert) ----------------
__global__ void router_kernel(const float* __restrict__ x, const float* __restrict__ gw,
                              u16* __restrict__ xb,
                              int* __restrict__ topk_id, float* __restrict__ topk_w) {
    const int wv = threadIdx.x >> 6, l = threadIdx.x & 63;
    const int t = blockIdx.x * 4 + wv;
    const float* xt = x + (size_t)t * DM;
    u16* xbt = xb + (size_t)t * DM;
    float acc[NE] = {0.f,0.f,0.f,0.f,0.f,0.f,0.f,0.f};
    for (int d = l * 4; d < DM; d += 256) {
        const float4 xv = *(const float4*)(xt + d);
        u16x4 o; o[0] = f2bf(xv.x); o[1] = f2bf(xv.y); o[2] = f2bf(xv.z); o[3] = f2bf(xv.w);
        *(u16x4*)(xbt + d) = o;
#pragma unroll
        for (int e = 0; e < NE; e++) {
            const float4 w4 = *(const float4*)(gw + e * DM + d);
            acc[e] += xv.x * w4.x + xv.y * w4.y + xv.z * w4.z + xv.w * w4.w;
        }
    }
#pragma unroll
    for (int e = 0; e < NE; e++)
#pragma unroll
        for (int off = 32; off > 0; off >>= 1) acc[e] += __shfl_xor(acc[e], off, 64);
    if (l == 0) {
        float m = acc[0];
#pragma unroll
        for (int e = 1; e < NE; e++) m = fmaxf(m, acc[e]);
        float p[NE];
#pragma unroll
        for (int e = 0; e < NE; e++) p[e] = __expf(acc[e] - m);
        int i1 = 0; float b1 = p[0];
#pragma unroll
        for (int e = 1; e < NE; e++) if (p[e] > b1) { b1 = p[e]; i1 = e; }
        int i2 = -1; float b2 = -1.f;
#pragma unroll
        for (int e = 0; e < NE; e++) if (e != i1 && p[e] > b2) { b2 = p[e]; i2 = e; }
        const float s = b1 + b2;
        topk_id[2*t] = i1; topk_id[2*t+1] = i2;
        topk_w[2*t] = b1 / s; topk_w[2*t+1] = b2 / s;
    }
}

// ---------------- deterministic expert scan / permutation (128-padded) ----------------
__global__ void scan_kernel(const int* __restrict__ topk_id, const float* __restrict__ topk_w,
                            int* __restrict__ perm_token, float* __restrict__ slot_w,
                            int* __restrict__ tk_slot, int* __restrict__ tile_e) {
    const int e = blockIdx.x;
    const int tid = threadIdx.x;
    __shared__ int cnt[NE];
    __shared__ int tsum[256];
    int ids[16];
#pragma unroll
    for (int j = 0; j < 16; j++) ids[j] = topk_id[tid * 16 + j];
    if (tid < NE) cnt[tid] = 0;
    __syncthreads();
#pragma unroll
    for (int e2 = 0; e2 < NE; e2++) {
        int c = 0;
#pragma unroll
        for (int j = 0; j < 16; j++) c += (ids[j] == e2);
        if (c) atomicAdd(&cnt[e2], c);
    }
    int mySum = 0;
#pragma unroll
    for (int j = 0; j < 16; j++) mySum += (ids[j] == e);
    tsum[tid] = mySum;
    __syncthreads();
    if (tid == 0) { int run = 0; for (int i = 0; i < 256; i++) { int v = tsum[i]; tsum[i] = run; run += v; } }
    __syncthreads();
    int poff = 0;
#pragma unroll
    for (int e2 = 0; e2 < NE; e2++) { int p = (cnt[e2] + 127) & ~127; if (e2 < e) poff += p; }
    const int padded_e = (cnt[e] + 127) & ~127;
    int run = tsum[tid];
#pragma unroll
    for (int j = 0; j < 16; j++) {
        if (ids[j] == e) {
            const int i = tid * 16 + j;
            const int slot = poff + run;
            perm_token[slot] = i >> 1;
            slot_w[slot] = topk_w[i];
            tk_slot[i] = slot;
            run++;
        }
    }
    for (int r = cnt[e] + tid; r < padded_e; r += 256) { perm_token[poff + r] = 0; slot_w[poff + r] = 0.f; }
    if (tid == 0) for (int tt = poff >> 7; tt < (poff + padded_e) >> 7; tt++) tile_e[tt] = e;
    if (e == 0 && tid == 1) {
        int ptot = 0;
#pragma unroll
        for (int e2 = 0; e2 < NE; e2++) ptot += (cnt[e2] + 127) & ~127;
        for (int tt = ptot >> 7; tt < MT_ROUTED; tt++) tile_e[tt] = -1;
        for (int tt = MT_ROUTED; tt < MT_TOTAL; tt++) tile_e[tt] = 8;
    }
}

// ---------------- GEMM1: 128xM x 64h-cols, single-buffer, XCD-swizzled, 4 blocks/CU ----------------
__global__ __launch_bounds__(256, 4)
void gemm1_kernel(const u16* __restrict__ xb,
                  const u16* __restrict__ wgT, const u16* __restrict__ wuT,
                  const u16* __restrict__ swgT, const u16* __restrict__ swuT,
                  const int* __restrict__ perm_token, const float* __restrict__ slot_w,
                  const int* __restrict__ tile_e, u16* __restrict__ hbuf) {
    const int bid = blockIdx.x;
    const int swz = (bid & 7) * 154 + (bid >> 3);   // 1232 = 8*154
    const int mtile = swz % 56, ntile = swz / 56;   // ntile 0..21
    const int e = tile_e[mtile];
    if (e < 0) return;
    __shared__ u16 lA[128 * 64], lB[128 * 64];
    __shared__ int lTok[128];
    __shared__ float lW[128];
    const int tid = threadIdx.x, l = tid & 63, w = tid >> 6;
    const bool sh = (e == 8);
    const int slot_base = sh ? (ROUTED_CAP + (mtile - MT_ROUTED) * 128) : mtile * 128;
    if (tid < 128) {
        if (sh) { lTok[tid] = (mtile - MT_ROUTED) * 128 + tid; lW[tid] = 1.0f; }
        else    { lTok[tid] = perm_token[slot_base + tid]; lW[tid] = slot_w[slot_base + tid]; }
    }
    __syncthreads();
    const u16* Bg = sh ? swgT : (wgT + (size_t)e * FF * DM);
    const u16* Bu = sh ? swuT : (wuT + (size_t)e * FF * DM);
    const int n0 = ntile * 64;
    const u16* aSrc[4]; const u16* bSrc[4]; int ldsOff[4];
#pragma unroll
    for (int i = 0; i < 4; i++) {
        const int row = i * 32 + w * 8 + (l >> 3);
        const int ch = (l & 7) ^ (row & 7);
        ldsOff[i] = (i * 32 + w * 8) * 64;
        aSrc[i] = xb + (size_t)lTok[row] * DM + ch * 8;
        const u16* bbase = (i < 2) ? (Bg + (size_t)(n0 + row) * DM)
                                   : (Bu + (size_t)(n0 + row - 64) * DM);
        bSrc[i] = bbase + ch * 8;
    }
    f32x4 acc[2][8] = {};
    const int wm = w * 32;
    for (int k0 = 0; k0 < DM; k0 += 64) {
        __syncthreads();
#pragma unroll
        for (int i = 0; i < 4; i++) { gll16(aSrc[i] + k0, lA + ldsOff[i]); gll16(bSrc[i] + k0, lB + ldsOff[i]); }
        __syncthreads();
#pragma unroll
        for (int kk = 0; kk < 64; kk += 32) {
            bf16x8 af[2], bf_[8];
#pragma unroll
            for (int mi = 0; mi < 2; mi++) {
                const int row = wm + mi * 16 + (l & 15);
                const int ch = ((kk >> 3) + (l >> 4)) ^ (row & 7);
                af[mi] = *(const bf16x8*)(lA + row * 64 + ch * 8);
            }
#pragma unroll
            for (int ni = 0; ni < 8; ni++) {
                const int row = ni * 16 + (l & 15);
                const int ch = ((kk >> 3) + (l >> 4)) ^ (row & 7);
                bf_[ni] = *(const bf16x8*)(lB + row * 64 + ch * 8);
            }
#pragma unroll
            for (int mi = 0; mi < 2; mi++)
#pragma unroll
                for (int ni = 0; ni < 8; ni++)
                    acc[mi][ni] = __builtin_amdgcn_mfma_f32_16x16x32_bf16(af[mi], bf_[ni], acc[mi][ni], 0, 0, 0);
        }
    }
#pragma unroll
    for (int mi = 0; mi < 2; mi++)
#pragma unroll
        for (int r = 0; r < 4; r++) {
            const int m = wm + mi * 16 + (l >> 4) * 4 + r;
            const float wgt = lW[m];
#pragma unroll
            for (int ni = 0; ni < 4; ni++) {
                const int n = ni * 16 + (l & 15);
                const float g = acc[mi][ni][r], u = acc[mi][ni + 4][r];
                const float h = g * (1.f / (1.f + __expf(-g))) * u * wgt;
                hbuf[(size_t)(slot_base + m) * FF + n0 + n] = f2bf(h);
            }
        }
}

// ---------------- GEMM2: 128xM x 64xN, single-buffer, XCD-swizzled, 5 blocks/CU ----------------
__global__ __launch_bounds__(256, 5)
void gemm2_kernel(const u16* __restrict__ hbuf, const u16* __restrict__ wdT,
                  const u16* __restrict__ swdT, const int* __restrict__ tile_e,
                  u16* __restrict__ dn) {
    const int bid = blockIdx.x;
    const int swz = (bid & 7) * 224 + (bid >> 3);   // 1792 = 8*224
    const int mtile = swz % 56, ntile = swz / 56;   // ntile 0..31
    const int e = tile_e[mtile];
    if (e < 0) return;
    __shared__ u16 lA[128 * 64], lB[64 * 64];
    const int tid = threadIdx.x, l = tid & 63, w = tid >> 6;
    const bool sh = (e == 8);
    const int slot_base = sh ? (ROUTED_CAP + (mtile - MT_ROUTED) * 128) : mtile * 128;
    const u16* Bp = sh ? swdT : (wdT + (size_t)e * DM * FF);
    const int n0 = ntile * 64;
    const u16* aSrc[4]; const u16* bSrc[2]; int aOff[4], bOff[2];
#pragma unroll
    for (int i = 0; i < 4; i++) {
        const int row = i * 32 + w * 8 + (l >> 3);
        const int ch = (l & 7) ^ (row & 7);
        aOff[i] = (i * 32 + w * 8) * 64;
        aSrc[i] = hbuf + (size_t)(slot_base + row) * FF + ch * 8;
    }
#pragma unroll
    for (int i = 0; i < 2; i++) {
        const int row = i * 32 + w * 8 + (l >> 3);
        const int ch = (l & 7) ^ (row & 7);
        bOff[i] = (i * 32 + w * 8) * 64;
        bSrc[i] = Bp + (size_t)(n0 + row) * FF + ch * 8;
    }
    f32x4 acc[2][4] = {};
    const int wm = w * 32;
    for (int k0 = 0; k0 < FF; k0 += 64) {
        __syncthreads();
#pragma unroll
        for (int i = 0; i < 4; i++) gll16(aSrc[i] + k0, lA + aOff[i]);
#pragma unroll
        for (int i = 0; i < 2; i++) gll16(bSrc[i] + k0, lB + bOff[i]);
        __syncthreads();
#pragma unroll
        for (int kk = 0; kk < 64; kk += 32) {
            bf16x8 af[2], bf_[4];
#pragma unroll
            for (int mi = 0; mi < 2; mi++) {
                const int row = wm + mi * 16 + (l & 15);
                const int ch = ((kk >> 3) + (l >> 4)) ^ (row & 7);
                af[mi] = *(const bf16x8*)(lA + row * 64 + ch * 8);
            }
#pragma unroll
            for (int ni = 0; ni < 4; ni++) {
                const int row = ni * 16 + (l & 15);
                const int ch = ((kk >> 3) + (l >> 4)) ^ (row & 7);
                bf_[ni] = *(const bf16x8*)(lB + row * 64 + ch * 8);
            }
#pragma unroll
            for (int mi = 0; mi < 2; mi++)
#pragma unroll
                for (int ni = 0; ni < 4; ni++)
                    acc[mi][ni] = __builtin_amdgcn_mfma_f32_16x16x32_bf16(af[mi], bf_[ni], acc[mi][ni], 0, 0, 0);
        }
    }
#pragma unroll
    for (int mi = 0; mi < 2; mi++)
#pragma unroll
        for (int r = 0; r < 4; r++) {
            const int m = wm + mi * 16 + (l >> 4) * 4 + r;
#pragma unroll
            for (int ni = 0; ni < 4; ni++) {
                const int n = ni * 16 + (l & 15);
                dn[(size_t)(slot_base + m) * DM + n0 + n] = f2bf(acc[mi][ni][r]);
            }
        }
}

// ---------------- combine: out[t] = dn[s1] + dn[s2] + dn[shared] ----------------
__global__ void combine_kernel(const u16* __restrict__ dn, const int* __restrict__ tk_slot,
                               float* __restrict__ out) {
    const int i = blockIdx.x * 256 + threadIdx.x;
    const int base = i * 8;
    const int t = base >> 11, d = base & 2047;
    const int s1 = tk_slot[2 * t], s2 = tk_slot[2 * t + 1];
    const bf16x8 a = *(const bf16x8*)(dn + (size_t)s1 * DM + d);
    const bf16x8 b = *(const bf16x8*)(dn + (size_t)s2 * DM + d);
    const bf16x8 c = *(const bf16x8*)(dn + (size_t)(ROUTED_CAP + t) * DM + d);
    float o[8];
#pragma unroll
    for (int j = 0; j < 8; j++)
        o[j] = bf2f((u16)a[j]) + bf2f((u16)b[j]) + bf2f((u16)c[j]);
    float4 lo, hi;
    lo.x = o[0]; lo.y = o[1]; lo.z = o[2]; lo.w = o[3];
    hi.x = o[4]; hi.y = o[5]; hi.z = o[6]; hi.w = o[7];
    *(float4*)(out + base) = lo;
    *(float4*)(out + base + 4) = hi;
}

// ---------------- launch ----------------
extern "C" void kernel_launch(void* const* d_in, const int* in_sizes, int n_in,
                              void* d_out, int out_size, void* d_ws, size_t ws_size,
                              hipStream_t stream) {
    (void)in_sizes; (void)n_in; (void)out_size; (void)ws_size;
    const float* x   = (const float*)d_in[0];
    const float* gw  = (const float*)d_in[1];
    const float* wg  = (const float*)d_in[2];
    const float* wu  = (const float*)d_in[3];
    const float* wd  = (const float*)d_in[4];
    const float* swg = (const float*)d_in[5];
    const float* swu = (const float*)d_in[6];
    const float* swd = (const float*)d_in[7];
    float* out = (float*)d_out;
    char* ws = (char*)d_ws;

    u16*   xb    = (u16*)(ws + OFF_XB);
    u16*   wgT   = (u16*)(ws + OFF_WGT);
    u16*   wuT   = (u16*)(ws + OFF_WUT);
    u16*   wdT   = (u16*)(ws + OFF_WDT);
    u16*   swgT  = (u16*)(ws + OFF_SWG);
    u16*   swuT  = (u16*)(ws + OFF_SWU);
    u16*   swdT  = (u16*)(ws + OFF_SWD);
    u16*   hbuf  = (u16*)(ws + OFF_H);
    u16*   dn    = (u16*)(ws + OFF_DN);
    int*   tid_  = (int*)(ws + OFF_TID);
    float* tw    = (float*)(ws + OFF_TW);
    int*   perm  = (int*)(ws + OFF_PERM);
    float* slw   = (float*)(ws + OFF_SW_S);
    int*   tks   = (int*)(ws + OFF_TKS);
    int*   te    = (int*)(ws + OFF_TE);

    router_kernel<<<T_TOK / 4, 256, 0, stream>>>(x, gw, xb, tid_, tw);
    scan_kernel<<<NE, 256, 0, stream>>>(tid_, tw, perm, slw, tks, te);
    tcvt_kernel<<<dim3(176, 1, 27), 256, 0, stream>>>(wg, wu, swg, swu, wd, swd,
                                                      wgT, wuT, swgT, swuT, wdT, swdT);
    gemm1_kernel<<<1232, 256, 0, stream>>>(xb, wgT, wuT, swgT, swuT, perm, slw, te, hbuf);
    gemm2_kernel<<<1792, 256, 0, stream>>>(hbuf, wdT, swdT, te, dn);
    combine_kernel<<<(T_TOK * DM / 8) / 256, 256, 0, stream>>>(dn, tks, out);
}